// Round 9
// baseline (227.317 us; speedup 1.0000x reference)
//
#include <hip/hip_runtime.h>
#include <hip/hip_bf16.h>
#include <cstdint>

#define T_TOK 1024
#define H_DIM 1024
#define I_DIM 512
#define E_NUM 16
#define TOPK  4

typedef __bf16 bf16;
typedef __bf16 bf16x8 __attribute__((ext_vector_type(8)));
typedef float  f32x4  __attribute__((ext_vector_type(4)));

// ---------------- init: zero out, build shared-expert list ----------------
__global__ void init_kernel(float* __restrict__ out, int* __restrict__ counts,
                            int* __restrict__ tok, float* __restrict__ wt,
                            int* __restrict__ slot) {
  int i = blockIdx.x * 256 + threadIdx.x;   // 0..262143
  f32x4* o4 = (f32x4*)out;                  // 1M floats = 262144 float4
  o4[i] = f32x4{0.f, 0.f, 0.f, 0.f};
  if (i == 0) counts[E_NUM] = T_TOK;
  if (i < T_TOK) {
    tok [E_NUM * T_TOK + i] = i;
    wt  [E_NUM * T_TOK + i] = 1.0f;
    slot[E_NUM * T_TOK + i] = T_TOK * TOPK + i;
  }
}

// ---------------- convert x fp32 -> bf16 ----------------
__global__ void convx_kernel(const float* __restrict__ x, bf16* __restrict__ xb) {
  int i = blockIdx.x * 256 + threadIdx.x;   // 131072 threads
  float4 f0 = ((const float4*)x)[i * 2];
  float4 f1 = ((const float4*)x)[i * 2 + 1];
  bf16x8 p;
  p[0]=(bf16)f0.x; p[1]=(bf16)f0.y; p[2]=(bf16)f0.z; p[3]=(bf16)f0.w;
  p[4]=(bf16)f1.x; p[5]=(bf16)f1.y; p[6]=(bf16)f1.z; p[7]=(bf16)f1.w;
  ((bf16x8*)xb)[i] = p;
}

// ---------------- LDS-tiled transpose+convert: src fp32 [K][N] -> dst bf16 [N][K] ----------------
__global__ void transpose_conv_kernel(const float* __restrict__ src, bf16* __restrict__ dst,
                                      int K, int N) {
  __shared__ __align__(16) bf16 tile[64 * 72];  // [n][k], stride 72 elem
  const int tid = threadIdx.x;
  const size_t mat = (size_t)blockIdx.z * K * N;
  const int kb = blockIdx.y * 64, nb = blockIdx.x * 64;

  {
    const int k = tid >> 2, nq = (tid & 3) * 16;
    const float4* s = (const float4*)(src + mat + (size_t)(kb + k) * N + nb + nq);
    float4 f[4];
#pragma unroll
    for (int q = 0; q < 4; ++q) f[q] = s[q];
    const float* fs = (const float*)f;
#pragma unroll
    for (int j = 0; j < 16; ++j) tile[(nq + j) * 72 + k] = (bf16)fs[j];
  }
  __syncthreads();
  {
    const int n = tid >> 2, kq = (tid & 3) * 16;
    bf16x8 p0 = *(const bf16x8*)(tile + n * 72 + kq);
    bf16x8 p1 = *(const bf16x8*)(tile + n * 72 + kq + 8);
    bf16* d = dst + mat + (size_t)(nb + n) * K + kb + kq;
    *(bf16x8*)d = p0;
    *(bf16x8*)(d + 8) = p1;
  }
}

// ---------------- router phase 1: scores + in-register top-4, dense writes ----------------
__global__ void router_score_kernel(const float* __restrict__ x, const float* __restrict__ gw,
                                    int* __restrict__ topk_e, float* __restrict__ topk_w) {
  const int wave = threadIdx.x >> 6, lane = threadIdx.x & 63;
  const int t = blockIdx.x * 4 + wave;
  const float4* xr = (const float4*)(x + (size_t)t * H_DIM);

  float4 xv[4];
#pragma unroll
  for (int j = 0; j < 4; ++j) xv[j] = xr[lane + 64 * j];

  float p[E_NUM];
#pragma unroll
  for (int e = 0; e < E_NUM; ++e) {
    const float4* gr = (const float4*)(gw + (size_t)e * H_DIM);
    float s = 0.f;
#pragma unroll
    for (int j = 0; j < 4; ++j) {
      float4 g = gr[lane + 64 * j];
      s += xv[j].x * g.x + xv[j].y * g.y + xv[j].z * g.z + xv[j].w * g.w;
    }
    p[e] = s;
  }
#pragma unroll
  for (int off = 32; off > 0; off >>= 1) {
#pragma unroll
    for (int e = 0; e < E_NUM; ++e) p[e] += __shfl_xor(p[e], off);
  }
  float rem[E_NUM];
#pragma unroll
  for (int e = 0; e < E_NUM; ++e) rem[e] = 1.f / (1.f + __expf(-p[e]));
  float vals[TOPK]; int idx[TOPK];
#pragma unroll
  for (int k = 0; k < TOPK; ++k) {
    float m = rem[0]; int mi = 0;
#pragma unroll
    for (int e = 1; e < E_NUM; ++e) {
      if (rem[e] > m) { m = rem[e]; mi = e; }
    }
    vals[k] = m; idx[k] = mi;
#pragma unroll
    for (int e = 0; e < E_NUM; ++e) rem[e] = (e == mi) ? -1e30f : rem[e];
  }
  if (lane == 0) {
    float inv = 1.f / (vals[0] + vals[1] + vals[2] + vals[3]);
    int4 ids; ids.x = idx[0]; ids.y = idx[1]; ids.z = idx[2]; ids.w = idx[3];
    float4 w4; w4.x = vals[0]*inv; w4.y = vals[1]*inv; w4.z = vals[2]*inv; w4.w = vals[3]*inv;
    ((int4*)topk_e)[t] = ids;
    ((float4*)topk_w)[t] = w4;
  }
}

// ---------------- router phase 2: per-expert list build via ballot prefix (no atomics) ----------------
__global__ void router_build_kernel(const int* __restrict__ topk_e, const float* __restrict__ topk_w,
                                    int* __restrict__ counts, int* __restrict__ tok,
                                    float* __restrict__ wt, int* __restrict__ slot) {
  const int e = blockIdx.x;  // 0..15
  const int tid = threadIdx.x, wave = tid >> 6, lane = tid & 63;
  __shared__ int wsum[4];
  int base = 0;
  for (int r = 0; r < 4; ++r) {
    int t = r * 256 + tid;
    int4 ids = ((const int4*)topk_e)[t];
    int match = -1;
    if (ids.x == e) match = 0;
    if (ids.y == e) match = 1;
    if (ids.z == e) match = 2;
    if (ids.w == e) match = 3;
    unsigned long long b = __ballot(match >= 0);
    int prefix = __popcll(b & ((1ull << lane) - 1ull));
    if (lane == 0) wsum[wave] = __popcll(b);
    __syncthreads();
    int wbase = 0;
#pragma unroll
    for (int wv = 0; wv < 4; ++wv) wbase += (wv < wave) ? wsum[wv] : 0;
    int total = wsum[0] + wsum[1] + wsum[2] + wsum[3];
    if (match >= 0) {
      int pos = base + wbase + prefix;
      tok [e * T_TOK + pos] = t;
      wt  [e * T_TOK + pos] = topk_w[t * 4 + match];
      slot[e * T_TOK + pos] = t * 4 + match;
    }
    base += total;
    __syncthreads();
  }
  if (tid == 0) counts[e] = base;
}

// ---------------- GEMM1: barrier-free register-direct MFMA ----------------
// Per wave: 32 tokens x (32 gate + 32 up cols). No LDS, no barriers — fragments
// loaded straight from global bf16 (16B/lane dwordx4), double-buffered in regs.
__global__ __launch_bounds__(256, 4)
void gemm1_kernel(const bf16* __restrict__ xb, const bf16* __restrict__ wguT,
                  const bf16* __restrict__ sguT, const int* __restrict__ counts,
                  const int* __restrict__ tok, const int* __restrict__ slot,
                  bf16* __restrict__ hbuf) {
  const int e   = blockIdx.z;
  const int cnt = counts[e];
  const int rt  = blockIdx.y;
  if (rt * 128 >= cnt) return;
  const int nb = blockIdx.x * 32;  // h col base within I=512
  const bf16* BT = (e < E_NUM) ? (wguT + (size_t)e * (2 * I_DIM) * H_DIM) : sguT;

  const int tid = threadIdx.x, wave = tid >> 6, lane = tid & 63;
  const int fr = lane & 15, kg = lane >> 4;
  const int m0 = rt * 128 + wave * 32;
  if (m0 >= cnt) return;  // whole wave out of range (divergence at block granularity only if partial)

  int r0 = m0 + fr;       r0 = r0 < cnt ? r0 : cnt - 1;
  int r1 = m0 + 16 + fr;  r1 = r1 < cnt ? r1 : cnt - 1;
  const bf16* aP0 = xb + (size_t)tok[e * T_TOK + r0] * H_DIM + kg * 8;
  const bf16* aP1 = xb + (size_t)tok[e * T_TOK + r1] * H_DIM + kg * 8;
  const bf16* gP0 = BT + (size_t)(nb + fr) * H_DIM + kg * 8;
  const bf16* gP1 = BT + (size_t)(nb + 16 + fr) * H_DIM + kg * 8;
  const bf16* uP0 = BT + (size_t)(I_DIM + nb + fr) * H_DIM + kg * 8;
  const bf16* uP1 = BT + (size_t)(I_DIM + nb + 16 + fr) * H_DIM + kg * 8;

  f32x4 accg[2][2], accu[2][2];
#pragma unroll
  for (int i = 0; i < 2; ++i)
#pragma unroll
    for (int j = 0; j < 2; ++j) { accg[i][j] = f32x4{0,0,0,0}; accu[i][j] = f32x4{0,0,0,0}; }

  // k=0 fragments
  bf16x8 a0 = *(const bf16x8*)(aP0);
  bf16x8 a1 = *(const bf16x8*)(aP1);
  bf16x8 g0 = *(const bf16x8*)(gP0);
  bf16x8 g1 = *(const bf16x8*)(gP1);
  bf16x8 u0 = *(const bf16x8*)(uP0);
  bf16x8 u1 = *(const bf16x8*)(uP1);

  for (int k = 32; k <= H_DIM; k += 32) {
    bf16x8 a0n, a1n, g0n, g1n, u0n, u1n;
    if (k < H_DIM) {
      a0n = *(const bf16x8*)(aP0 + k);
      a1n = *(const bf16x8*)(aP1 + k);
      g0n = *(const bf16x8*)(gP0 + k);
      g1n = *(const bf16x8*)(gP1 + k);
      u0n = *(const bf16x8*)(uP0 + k);
      u1n = *(const bf16x8*)(uP1 + k);
    }
    accg[0][0] = __builtin_amdgcn_mfma_f32_16x16x32_bf16(a0, g0, accg[0][0], 0, 0, 0);
    accg[0][1] = __builtin_amdgcn_mfma_f32_16x16x32_bf16(a0, g1, accg[0][1], 0, 0, 0);
    accg[1][0] = __builtin_amdgcn_mfma_f32_16x16x32_bf16(a1, g0, accg[1][0], 0, 0, 0);
    accg[1][1] = __builtin_amdgcn_mfma_f32_16x16x32_bf16(a1, g1, accg[1][1], 0, 0, 0);
    accu[0][0] = __builtin_amdgcn_mfma_f32_16x16x32_bf16(a0, u0, accu[0][0], 0, 0, 0);
    accu[0][1] = __builtin_amdgcn_mfma_f32_16x16x32_bf16(a0, u1, accu[0][1], 0, 0, 0);
    accu[1][0] = __builtin_amdgcn_mfma_f32_16x16x32_bf16(a1, u0, accu[1][0], 0, 0, 0);
    accu[1][1] = __builtin_amdgcn_mfma_f32_16x16x32_bf16(a1, u1, accu[1][1], 0, 0, 0);
    a0 = a0n; a1 = a1n; g0 = g0n; g1 = g1n; u0 = u0n; u1 = u1n;
  }

  // epilogue: swiglu, scatter-store h[slot][col] as bf16
#pragma unroll
  for (int mi = 0; mi < 2; ++mi) {
#pragma unroll
    for (int j = 0; j < 4; ++j) {
      int grow = m0 + mi * 16 + kg * 4 + j;
      if (grow < cnt) {
        bf16* hr = hbuf + (size_t)slot[e * T_TOK + grow] * I_DIM;
#pragma unroll
        for (int ni = 0; ni < 2; ++ni) {
          float g = accg[mi][ni][j], u = accu[mi][ni][j];
          float h = (g / (1.f + __expf(-g))) * u;
          hr[nb + ni * 16 + fr] = (bf16)h;
        }
      }
    }
  }
}

// ---------------- GEMM2: barrier-free register-direct MFMA ----------------
// Per wave: 32 tokens x 64 out cols. Weighted atomicAdd into out.
__global__ __launch_bounds__(256, 4)
void gemm2_kernel(const bf16* __restrict__ hbuf, const bf16* __restrict__ wdT,
                  const bf16* __restrict__ sdT, const int* __restrict__ counts,
                  const int* __restrict__ tok, const float* __restrict__ wt,
                  const int* __restrict__ slot, float* __restrict__ out) {
  const int e   = blockIdx.z;
  const int cnt = counts[e];
  const int rt  = blockIdx.y;
  if (rt * 128 >= cnt) return;
  const int nb = blockIdx.x * 64;  // out col base within H=1024
  const bf16* BT = (e < E_NUM) ? (wdT + (size_t)e * H_DIM * I_DIM) : sdT;

  const int tid = threadIdx.x, wave = tid >> 6, lane = tid & 63;
  const int fr = lane & 15, kg = lane >> 4;
  const int m0 = rt * 128 + wave * 32;
  if (m0 >= cnt) return;

  int r0 = m0 + fr;       r0 = r0 < cnt ? r0 : cnt - 1;
  int r1 = m0 + 16 + fr;  r1 = r1 < cnt ? r1 : cnt - 1;
  const bf16* aP0 = hbuf + (size_t)slot[e * T_TOK + r0] * I_DIM + kg * 8;
  const bf16* aP1 = hbuf + (size_t)slot[e * T_TOK + r1] * I_DIM + kg * 8;
  const bf16* bP0 = BT + (size_t)(nb      + fr) * I_DIM + kg * 8;
  const bf16* bP1 = BT + (size_t)(nb + 16 + fr) * I_DIM + kg * 8;
  const bf16* bP2 = BT + (size_t)(nb + 32 + fr) * I_DIM + kg * 8;
  const bf16* bP3 = BT + (size_t)(nb + 48 + fr) * I_DIM + kg * 8;

  f32x4 acc[2][4];
#pragma unroll
  for (int i = 0; i < 2; ++i)
#pragma unroll
    for (int j = 0; j < 4; ++j) acc[i][j] = f32x4{0,0,0,0};

  bf16x8 a0 = *(const bf16x8*)(aP0);
  bf16x8 a1 = *(const bf16x8*)(aP1);
  bf16x8 b0 = *(const bf16x8*)(bP0);
  bf16x8 b1 = *(const bf16x8*)(bP1);
  bf16x8 b2 = *(const bf16x8*)(bP2);
  bf16x8 b3 = *(const bf16x8*)(bP3);

  for (int k = 32; k <= I_DIM; k += 32) {
    bf16x8 a0n, a1n, b0n, b1n, b2n, b3n;
    if (k < I_DIM) {
      a0n = *(const bf16x8*)(aP0 + k);
      a1n = *(const bf16x8*)(aP1 + k);
      b0n = *(const bf16x8*)(bP0 + k);
      b1n = *(const bf16x8*)(bP1 + k);
      b2n = *(const bf16x8*)(bP2 + k);
      b3n = *(const bf16x8*)(bP3 + k);
    }
    acc[0][0] = __builtin_amdgcn_mfma_f32_16x16x32_bf16(a0, b0, acc[0][0], 0, 0, 0);
    acc[0][1] = __builtin_amdgcn_mfma_f32_16x16x32_bf16(a0, b1, acc[0][1], 0, 0, 0);
    acc[0][2] = __builtin_amdgcn_mfma_f32_16x16x32_bf16(a0, b2, acc[0][2], 0, 0, 0);
    acc[0][3] = __builtin_amdgcn_mfma_f32_16x16x32_bf16(a0, b3, acc[0][3], 0, 0, 0);
    acc[1][0] = __builtin_amdgcn_mfma_f32_16x16x32_bf16(a1, b0, acc[1][0], 0, 0, 0);
    acc[1][1] = __builtin_amdgcn_mfma_f32_16x16x32_bf16(a1, b1, acc[1][1], 0, 0, 0);
    acc[1][2] = __builtin_amdgcn_mfma_f32_16x16x32_bf16(a1, b2, acc[1][2], 0, 0, 0);
    acc[1][3] = __builtin_amdgcn_mfma_f32_16x16x32_bf16(a1, b3, acc[1][3], 0, 0, 0);
    a0 = a0n; a1 = a1n; b0 = b0n; b1 = b1n; b2 = b2n; b3 = b3n;
  }

#pragma unroll
  for (int mi = 0; mi < 2; ++mi) {
#pragma unroll
    for (int j = 0; j < 4; ++j) {
      int grow = m0 + mi * 16 + kg * 4 + j;
      if (grow < cnt) {
        int   t = tok[e * T_TOK + grow];
        float w = wt [e * T_TOK + grow];
        float* orow = out + (size_t)t * H_DIM + nb + fr;
#pragma unroll
        for (int ni = 0; ni < 4; ++ni)
          atomicAdd(orow + ni * 16, w * acc[mi][ni][j]);
      }
    }
  }
}

extern "C" void kernel_launch(void* const* d_in, const int* in_sizes, int n_in,
                              void* d_out, int out_size, void* d_ws, size_t ws_size,
                              hipStream_t stream) {
  const float* x   = (const float*)d_in[0];
  const float* gw  = (const float*)d_in[1];
  const float* wgu = (const float*)d_in[2];
  const float* wd  = (const float*)d_in[3];
  const float* sgu = (const float*)d_in[4];
  const float* sd  = (const float*)d_in[5];
  float* out = (float*)d_out;

  char* ws = (char*)d_ws;
  int*   counts = (int*)  (ws);                 // 1 KB
  int*   tok    = (int*)  (ws + 1024);          // 68 KB
  float* wtA    = (float*)(ws + 70656);         // 68 KB
  int*   slotA  = (int*)  (ws + 140288);        // 68 KB
  int*   topk_e = (int*)  (ws + 209920);        // 16 KB
  float* topk_w = (float*)(ws + 226304);        // 16 KB
  bf16*  xb     = (bf16*) (ws + 245760);        // 2 MB
  bf16*  hbuf   = (bf16*) (ws + 2342912);       // 5.25 MB
  bf16*  wguT   = (bf16*) (ws + 7585792);       // 32 MB  [E][2I][H]
  bf16*  wdT    = (bf16*) (ws + 41140224);      // 16 MB  [E][H][I]
  bf16*  sguT   = (bf16*) (ws + 57917440);      // 2 MB   [2I][H]
  bf16*  sdT    = (bf16*) (ws + 60014592);      // 1 MB   [H][I]
  // total ~61.1 MB

  init_kernel<<<1024, 256, 0, stream>>>(out, counts, tok, wtA, slotA);
  convx_kernel<<<512, 256, 0, stream>>>(x, xb);
  transpose_conv_kernel<<<dim3(16, 16, E_NUM), 256, 0, stream>>>(wgu, wguT, H_DIM, 2 * I_DIM);
  transpose_conv_kernel<<<dim3(16,  8, E_NUM), 256, 0, stream>>>(wd,  wdT,  I_DIM, H_DIM);
  transpose_conv_kernel<<<dim3(16, 16, 1),     256, 0, stream>>>(sgu, sguT, H_DIM, 2 * I_DIM);
  transpose_conv_kernel<<<dim3(16,  8, 1),     256, 0, stream>>>(sd,  sdT,  I_DIM, H_DIM);
  router_score_kernel<<<T_TOK / 4, 256, 0, stream>>>(x, gw, topk_e, topk_w);
  router_build_kernel<<<E_NUM, 256, 0, stream>>>(topk_e, topk_w, counts, tok, wtA, slotA);
  gemm1_kernel<<<dim3(16, 8, 17), 256, 0, stream>>>(xb, wguT, sguT, counts, tok, slotA, hbuf);
  gemm2_kernel<<<dim3(16, 8, 17), 256, 0, stream>>>(hbuf, wdT, sdT, counts, tok, wtA, slotA, out);
}

// Round 10
// 122.479 us; speedup vs baseline: 1.8560x; 1.8560x over previous
//
#include <hip/hip_runtime.h>
#include <hip/hip_bf16.h>
#include <cstdint>

#define T_TOK 1024
#define H_DIM 1024
#define I_DIM 512
#define E_NUM 16
#define TOPK  4

typedef __bf16 bf16;
typedef __bf16 bf16x8 __attribute__((ext_vector_type(8)));
typedef float  f32x4  __attribute__((ext_vector_type(4)));

#define GLOAD16(g, l)                                                                   \
  __builtin_amdgcn_global_load_lds((const __attribute__((address_space(1))) void*)(g),  \
                                   (__attribute__((address_space(3))) void*)(l), 16, 0, 0)

// ---------------- init: counts + shared-expert list (out zeroing no longer needed) ----------------
__global__ void init_kernel(int* __restrict__ counts, int* __restrict__ tok,
                            float* __restrict__ wt, int* __restrict__ slot) {
  int i = blockIdx.x * 256 + threadIdx.x;   // 0..1023
  if (i == 0) counts[E_NUM] = T_TOK;
  tok [E_NUM * T_TOK + i] = i;
  wt  [E_NUM * T_TOK + i] = 1.0f;
  slot[E_NUM * T_TOK + i] = T_TOK * TOPK + i;
}

// ---------------- convert x fp32 -> bf16 ----------------
__global__ void convx_kernel(const float* __restrict__ x, bf16* __restrict__ xb) {
  int i = blockIdx.x * 256 + threadIdx.x;   // 131072 threads
  float4 f0 = ((const float4*)x)[i * 2];
  float4 f1 = ((const float4*)x)[i * 2 + 1];
  bf16x8 p;
  p[0]=(bf16)f0.x; p[1]=(bf16)f0.y; p[2]=(bf16)f0.z; p[3]=(bf16)f0.w;
  p[4]=(bf16)f1.x; p[5]=(bf16)f1.y; p[6]=(bf16)f1.z; p[7]=(bf16)f1.w;
  ((bf16x8*)xb)[i] = p;
}

// ---------------- LDS-tiled transpose+convert: [K][N] fp32 -> [N][K] bf16 ----------------
// z < 16: expert matrix e; z == 16: the shared matrix.
__global__ void transpose_conv_kernel(const float* __restrict__ srcE, bf16* __restrict__ dstE,
                                      const float* __restrict__ srcS, bf16* __restrict__ dstS,
                                      int K, int N) {
  __shared__ __align__(16) bf16 tile[64 * 72];  // [n][k], stride 72 elem
  const int tid = threadIdx.x;
  const int z = blockIdx.z;
  const float* src = (z < E_NUM) ? (srcE + (size_t)z * K * N) : srcS;
  bf16*       dst  = (z < E_NUM) ? (dstE + (size_t)z * K * N) : dstS;
  const int kb = blockIdx.y * 64, nb = blockIdx.x * 64;

  {
    const int k = tid >> 2, nq = (tid & 3) * 16;
    const float4* s = (const float4*)(src + (size_t)(kb + k) * N + nb + nq);
    float4 f[4];
#pragma unroll
    for (int q = 0; q < 4; ++q) f[q] = s[q];
    const float* fs = (const float*)f;
#pragma unroll
    for (int j = 0; j < 16; ++j) tile[(nq + j) * 72 + k] = (bf16)fs[j];
  }
  __syncthreads();
  {
    const int n = tid >> 2, kq = (tid & 3) * 16;
    bf16x8 p0 = *(const bf16x8*)(tile + n * 72 + kq);
    bf16x8 p1 = *(const bf16x8*)(tile + n * 72 + kq + 8);
    bf16* d = dst + (size_t)(nb + n) * K + kb + kq;
    *(bf16x8*)d = p0;
    *(bf16x8*)(d + 8) = p1;
  }
}

// ---------------- router phase 1: scores + in-register top-4, dense writes ----------------
__global__ void router_score_kernel(const float* __restrict__ x, const float* __restrict__ gw,
                                    int* __restrict__ topk_e, float* __restrict__ topk_w) {
  const int wave = threadIdx.x >> 6, lane = threadIdx.x & 63;
  const int t = blockIdx.x * 4 + wave;
  const float4* xr = (const float4*)(x + (size_t)t * H_DIM);

  float4 xv[4];
#pragma unroll
  for (int j = 0; j < 4; ++j) xv[j] = xr[lane + 64 * j];

  float p[E_NUM];
#pragma unroll
  for (int e = 0; e < E_NUM; ++e) {
    const float4* gr = (const float4*)(gw + (size_t)e * H_DIM);
    float s = 0.f;
#pragma unroll
    for (int j = 0; j < 4; ++j) {
      float4 g = gr[lane + 64 * j];
      s += xv[j].x * g.x + xv[j].y * g.y + xv[j].z * g.z + xv[j].w * g.w;
    }
    p[e] = s;
  }
#pragma unroll
  for (int off = 32; off > 0; off >>= 1) {
#pragma unroll
    for (int e = 0; e < E_NUM; ++e) p[e] += __shfl_xor(p[e], off);
  }
  float rem[E_NUM];
#pragma unroll
  for (int e = 0; e < E_NUM; ++e) rem[e] = 1.f / (1.f + __expf(-p[e]));
  float vals[TOPK]; int idx[TOPK];
#pragma unroll
  for (int k = 0; k < TOPK; ++k) {
    float m = rem[0]; int mi = 0;
#pragma unroll
    for (int e = 1; e < E_NUM; ++e) {
      if (rem[e] > m) { m = rem[e]; mi = e; }
    }
    vals[k] = m; idx[k] = mi;
#pragma unroll
    for (int e = 0; e < E_NUM; ++e) rem[e] = (e == mi) ? -1e30f : rem[e];
  }
  if (lane == 0) {
    float inv = 1.f / (vals[0] + vals[1] + vals[2] + vals[3]);
    int4 ids; ids.x = idx[0]; ids.y = idx[1]; ids.z = idx[2]; ids.w = idx[3];
    float4 w4; w4.x = vals[0]*inv; w4.y = vals[1]*inv; w4.z = vals[2]*inv; w4.w = vals[3]*inv;
    ((int4*)topk_e)[t] = ids;
    ((float4*)topk_w)[t] = w4;
  }
}

// ---------------- router phase 2: per-expert list build via ballot prefix (no atomics) ----------------
__global__ void router_build_kernel(const int* __restrict__ topk_e, const float* __restrict__ topk_w,
                                    int* __restrict__ counts, int* __restrict__ tok,
                                    float* __restrict__ wt, int* __restrict__ slot) {
  const int e = blockIdx.x;  // 0..15
  const int tid = threadIdx.x, wave = tid >> 6, lane = tid & 63;
  __shared__ int wsum[4];
  int base = 0;
  for (int r = 0; r < 4; ++r) {
    int t = r * 256 + tid;
    int4 ids = ((const int4*)topk_e)[t];
    int match = -1;
    if (ids.x == e) match = 0;
    if (ids.y == e) match = 1;
    if (ids.z == e) match = 2;
    if (ids.w == e) match = 3;
    unsigned long long b = __ballot(match >= 0);
    int prefix = __popcll(b & ((1ull << lane) - 1ull));
    if (lane == 0) wsum[wave] = __popcll(b);
    __syncthreads();
    int wbase = 0;
#pragma unroll
    for (int wv = 0; wv < 4; ++wv) wbase += (wv < wave) ? wsum[wv] : 0;
    int total = wsum[0] + wsum[1] + wsum[2] + wsum[3];
    if (match >= 0) {
      int pos = base + wbase + prefix;
      tok [e * T_TOK + pos] = t;
      wt  [e * T_TOK + pos] = topk_w[t * 4 + match];
      slot[e * T_TOK + pos] = t * 4 + match;
    }
    base += total;
    __syncthreads();
  }
  if (tid == 0) counts[e] = base;
}

// ---------------- GEMM1: gathered Xb [cnt,1024] @ WguT -> wt * swiglu -> h bf16 ----------------
// BM=64, BN=64 (64 gate + 64 up BT rows), BK=32, 4 waves (2x2), double-buffered LDS.
// Routing weight folded into h (linear through the down-projection).
__global__ __launch_bounds__(256, 4)
void gemm1_kernel(const bf16* __restrict__ xb, const bf16* __restrict__ wguT,
                  const bf16* __restrict__ sguT, const int* __restrict__ counts,
                  const int* __restrict__ tok, const float* __restrict__ wt,
                  const int* __restrict__ slot, bf16* __restrict__ hbuf) {
  const int e   = blockIdx.z;
  const int cnt = counts[e];
  const int rt  = blockIdx.y;
  if (rt * 64 >= cnt) return;
  const int nb = blockIdx.x * 64;  // h col base within I=512
  const bf16* BT = (e < E_NUM) ? (wguT + (size_t)e * (2 * I_DIM) * H_DIM) : sguT;

  __shared__ __align__(16) bf16 sA[2][64 * 32];
  __shared__ __align__(16) bf16 sG[2][64 * 32];
  __shared__ __align__(16) bf16 sU[2][64 * 32];

  const int tid = threadIdx.x, wave = tid >> 6, lane = tid & 63;
  const int wr = wave >> 1, wc = wave & 1;      // 2x2 wave grid over 64x64
  const int fr = lane & 15, kg = lane >> 4;
  const int lr = lane >> 2, lk = (lane & 3) * 8;

  int ar = rt * 64 + wave * 16 + lr;
  int arc = ar < cnt ? ar : cnt - 1;
  const bf16* aS = xb + (size_t)tok[e * T_TOK + arc] * H_DIM + lk;
  const bf16* gS = BT + (size_t)(nb + wave * 16 + lr) * H_DIM + lk;
  const bf16* uS = BT + (size_t)(I_DIM + nb + wave * 16 + lr) * H_DIM + lk;
  const int ldsOff = wave * 512;   // 16 rows * 32 k per wave

  f32x4 accg[2][2], accu[2][2];
#pragma unroll
  for (int i = 0; i < 2; ++i)
#pragma unroll
    for (int j = 0; j < 2; ++j) { accg[i][j] = f32x4{0,0,0,0}; accu[i][j] = f32x4{0,0,0,0}; }

  GLOAD16(aS, sA[0] + ldsOff);
  GLOAD16(gS, sG[0] + ldsOff);
  GLOAD16(uS, sU[0] + ldsOff);
  __syncthreads();

  int cur = 0;
  for (int k0 = 0; k0 < H_DIM; k0 += 32) {
    if (k0 + 32 < H_DIM) {
      GLOAD16(aS + k0 + 32, sA[cur ^ 1] + ldsOff);
      GLOAD16(gS + k0 + 32, sG[cur ^ 1] + ldsOff);
      GLOAD16(uS + k0 + 32, sU[cur ^ 1] + ldsOff);
    }
    bf16x8 a0 = *(const bf16x8*)(sA[cur] + (wr * 32      + fr) * 32 + kg * 8);
    bf16x8 a1 = *(const bf16x8*)(sA[cur] + (wr * 32 + 16 + fr) * 32 + kg * 8);
    bf16x8 g0 = *(const bf16x8*)(sG[cur] + (wc * 32      + fr) * 32 + kg * 8);
    bf16x8 g1 = *(const bf16x8*)(sG[cur] + (wc * 32 + 16 + fr) * 32 + kg * 8);
    bf16x8 u0 = *(const bf16x8*)(sU[cur] + (wc * 32      + fr) * 32 + kg * 8);
    bf16x8 u1 = *(const bf16x8*)(sU[cur] + (wc * 32 + 16 + fr) * 32 + kg * 8);
    accg[0][0] = __builtin_amdgcn_mfma_f32_16x16x32_bf16(a0, g0, accg[0][0], 0, 0, 0);
    accg[0][1] = __builtin_amdgcn_mfma_f32_16x16x32_bf16(a0, g1, accg[0][1], 0, 0, 0);
    accg[1][0] = __builtin_amdgcn_mfma_f32_16x16x32_bf16(a1, g0, accg[1][0], 0, 0, 0);
    accg[1][1] = __builtin_amdgcn_mfma_f32_16x16x32_bf16(a1, g1, accg[1][1], 0, 0, 0);
    accu[0][0] = __builtin_amdgcn_mfma_f32_16x16x32_bf16(a0, u0, accu[0][0], 0, 0, 0);
    accu[0][1] = __builtin_amdgcn_mfma_f32_16x16x32_bf16(a0, u1, accu[0][1], 0, 0, 0);
    accu[1][0] = __builtin_amdgcn_mfma_f32_16x16x32_bf16(a1, u0, accu[1][0], 0, 0, 0);
    accu[1][1] = __builtin_amdgcn_mfma_f32_16x16x32_bf16(a1, u1, accu[1][1], 0, 0, 0);
    __syncthreads();
    cur ^= 1;
  }

  // epilogue: h = wt * swiglu, scatter-store h[slot][col] as bf16
#pragma unroll
  for (int mi = 0; mi < 2; ++mi) {
#pragma unroll
    for (int j = 0; j < 4; ++j) {
      int grow = rt * 64 + wr * 32 + mi * 16 + kg * 4 + j;
      if (grow < cnt) {
        bf16* hr = hbuf + (size_t)slot[e * T_TOK + grow] * I_DIM;
        float w = wt[e * T_TOK + grow];
#pragma unroll
        for (int ni = 0; ni < 2; ++ni) {
          float g = accg[mi][ni][j], u = accu[mi][ni][j];
          float h = w * (g / (1.f + __expf(-g))) * u;
          hr[nb + wc * 32 + ni * 16 + fr] = (bf16)h;
        }
      }
    }
  }
}

// ---------------- GEMM2: gathered h [cnt,512] @ WdT -> plain stores into obuf[slot] ----------------
// BM=64, BN=128, BK=32, double-buffered. No atomics (slot-major output, reduced later).
__global__ __launch_bounds__(256, 4)
void gemm2_kernel(const bf16* __restrict__ hbuf, const bf16* __restrict__ wdT,
                  const bf16* __restrict__ sdT, const int* __restrict__ counts,
                  const int* __restrict__ slot, float* __restrict__ obuf) {
  const int e   = blockIdx.z;
  const int cnt = counts[e];
  const int rt  = blockIdx.y;
  if (rt * 64 >= cnt) return;
  const int nb = blockIdx.x * 128;
  const bf16* BT = (e < E_NUM) ? (wdT + (size_t)e * H_DIM * I_DIM) : sdT;

  __shared__ __align__(16) bf16 sA[2][64 * 32];
  __shared__ __align__(16) bf16 sB[2][128 * 32];

  const int tid = threadIdx.x, wave = tid >> 6, lane = tid & 63;
  const int wr = wave >> 1, wc = wave & 1;
  const int fr = lane & 15, kg = lane >> 4;
  const int lr = lane >> 2, lk = (lane & 3) * 8;

  int ar = rt * 64 + wave * 16 + lr;
  int arc = ar < cnt ? ar : cnt - 1;
  const bf16* aS  = hbuf + (size_t)slot[e * T_TOK + arc] * I_DIM + lk;
  const bf16* bS0 = BT + (size_t)(nb + wave * 32 + lr) * I_DIM + lk;
  const bf16* bS1 = bS0 + (size_t)16 * I_DIM;
  const int aOff  = wave * 512;
  const int bOff0 = wave * 1024;
  const int bOff1 = bOff0 + 512;

  f32x4 acc[2][4];
#pragma unroll
  for (int i = 0; i < 2; ++i)
#pragma unroll
    for (int j = 0; j < 4; ++j) acc[i][j] = f32x4{0,0,0,0};

  GLOAD16(aS,  sA[0] + aOff);
  GLOAD16(bS0, sB[0] + bOff0);
  GLOAD16(bS1, sB[0] + bOff1);
  __syncthreads();

  int cur = 0;
  for (int k0 = 0; k0 < I_DIM; k0 += 32) {
    if (k0 + 32 < I_DIM) {
      GLOAD16(aS  + k0 + 32, sA[cur ^ 1] + aOff);
      GLOAD16(bS0 + k0 + 32, sB[cur ^ 1] + bOff0);
      GLOAD16(bS1 + k0 + 32, sB[cur ^ 1] + bOff1);
    }
    bf16x8 a0 = *(const bf16x8*)(sA[cur] + (wr * 32      + fr) * 32 + kg * 8);
    bf16x8 a1 = *(const bf16x8*)(sA[cur] + (wr * 32 + 16 + fr) * 32 + kg * 8);
    bf16x8 b[4];
#pragma unroll
    for (int ni = 0; ni < 4; ++ni)
      b[ni] = *(const bf16x8*)(sB[cur] + (wc * 64 + ni * 16 + fr) * 32 + kg * 8);
#pragma unroll
    for (int ni = 0; ni < 4; ++ni) {
      acc[0][ni] = __builtin_amdgcn_mfma_f32_16x16x32_bf16(a0, b[ni], acc[0][ni], 0, 0, 0);
      acc[1][ni] = __builtin_amdgcn_mfma_f32_16x16x32_bf16(a1, b[ni], acc[1][ni], 0, 0, 0);
    }
    __syncthreads();
    cur ^= 1;
  }

#pragma unroll
  for (int mi = 0; mi < 2; ++mi) {
#pragma unroll
    for (int j = 0; j < 4; ++j) {
      int grow = rt * 64 + wr * 32 + mi * 16 + kg * 4 + j;
      if (grow < cnt) {
        float* orow = obuf + (size_t)slot[e * T_TOK + grow] * H_DIM + nb + wc * 64 + fr;
#pragma unroll
        for (int ni = 0; ni < 4; ++ni)
          orow[ni * 16] = acc[mi][ni][j];
      }
    }
  }
}

// ---------------- reduce: out[t] = sum_k obuf[t*4+k] + obuf[4096+t] ----------------
__global__ void reduce_kernel(const float* __restrict__ obuf, float* __restrict__ out) {
  const int t = blockIdx.x;
  const int c = threadIdx.x;  // 256 f32x4 chunks per row
  const f32x4* o4 = (const f32x4*)obuf;
  f32x4 s = o4[(size_t)(t * 4 + 0) * 256 + c];
  s += o4[(size_t)(t * 4 + 1) * 256 + c];
  s += o4[(size_t)(t * 4 + 2) * 256 + c];
  s += o4[(size_t)(t * 4 + 3) * 256 + c];
  s += o4[(size_t)(T_TOK * TOPK + t) * 256 + c];
  ((f32x4*)out)[(size_t)t * 256 + c] = s;
}

extern "C" void kernel_launch(void* const* d_in, const int* in_sizes, int n_in,
                              void* d_out, int out_size, void* d_ws, size_t ws_size,
                              hipStream_t stream) {
  const float* x   = (const float*)d_in[0];
  const float* gw  = (const float*)d_in[1];
  const float* wgu = (const float*)d_in[2];
  const float* wd  = (const float*)d_in[3];
  const float* sgu = (const float*)d_in[4];
  const float* sd  = (const float*)d_in[5];
  float* out = (float*)d_out;

  char* ws = (char*)d_ws;
  int*   counts = (int*)  (ws);                 // 1 KB
  int*   tok    = (int*)  (ws + 1024);          // 68 KB
  float* wtA    = (float*)(ws + 70656);         // 68 KB
  int*   slotA  = (int*)  (ws + 140288);        // 68 KB
  int*   topk_e = (int*)  (ws + 209920);        // 16 KB
  float* topk_w = (float*)(ws + 226304);        // 16 KB
  bf16*  xb     = (bf16*) (ws + 245760);        // 2 MB
  bf16*  hbuf   = (bf16*) (ws + 2342912);       // 5.25 MB
  bf16*  wguT   = (bf16*) (ws + 7585792);       // 32 MB  [E][2I][H]
  bf16*  wdT    = (bf16*) (ws + 41140224);      // 16 MB  [E][H][I]
  bf16*  sguT   = (bf16*) (ws + 57917440);      // 2 MB   [2I][H]
  bf16*  sdT    = (bf16*) (ws + 60014592);      // 1 MB   [H][I]
  // obuf (20 MB fp32 [5120][1024]) aliases the wguT region: wguT is dead after
  // gemm1, and each replay rewrites wguT (transpose) before gemm1 reads it.
  float* obuf   = (float*)(ws + 7585792);
  // total ws use ~61.1 MB

  init_kernel<<<4, 256, 0, stream>>>(counts, tok, wtA, slotA);
  convx_kernel<<<512, 256, 0, stream>>>(x, xb);
  transpose_conv_kernel<<<dim3(16, 16, 17), 256, 0, stream>>>(wgu, wguT, sgu, sguT, H_DIM, 2 * I_DIM);
  transpose_conv_kernel<<<dim3(16,  8, 17), 256, 0, stream>>>(wd,  wdT,  sd,  sdT,  I_DIM, H_DIM);
  router_score_kernel<<<T_TOK / 4, 256, 0, stream>>>(x, gw, topk_e, topk_w);
  router_build_kernel<<<E_NUM, 256, 0, stream>>>(topk_e, topk_w, counts, tok, wtA, slotA);
  gemm1_kernel<<<dim3(8, 16, 17), 256, 0, stream>>>(xb, wguT, sguT, counts, tok, wtA, slotA, hbuf);
  gemm2_kernel<<<dim3(8, 16, 17), 256, 0, stream>>>(hbuf, wdT, sdT, counts, slotA, obuf);
  reduce_kernel<<<T_TOK, 256, 0, stream>>>(obuf, out);
}

// Round 11
// 96.534 us; speedup vs baseline: 2.3548x; 1.2688x over previous
//
#include <hip/hip_runtime.h>
#include <hip/hip_bf16.h>
#include <cstdint>

#define T_TOK 1024
#define H_DIM 1024
#define I_DIM 512
#define E_NUM 16
#define TOPK  4

typedef __bf16 bf16;
typedef __bf16 bf16x8 __attribute__((ext_vector_type(8)));
typedef float  f32x4  __attribute__((ext_vector_type(4)));

#define GLOAD16(g, l)                                                                   \
  __builtin_amdgcn_global_load_lds((const __attribute__((address_space(1))) void*)(g),  \
                                   (__attribute__((address_space(3))) void*)(l), 16, 0, 0)

// ================= fused prep kernel =================
// flat grid: [0,4352)   T1: wgu/sgu transpose (K=1024,N=1024)
//            [4352,6528) T2: wd/sd transpose  (K=512, N=1024)
//            [6528,7040) convx (512 blocks)
//            [7040,7296) router_score (256 blocks, 4 tokens each)
//            [7296,7300) init shared-expert lists

__device__ __forceinline__ void transpose_tile(const float* __restrict__ src,
                                               bf16* __restrict__ dst, int K, int N,
                                               int kb, int nb, int tid, bf16* tile) {
  {
    const int k = tid >> 2, nq = (tid & 3) * 16;
    const float4* s = (const float4*)(src + (size_t)(kb + k) * N + nb + nq);
    float4 f[4];
#pragma unroll
    for (int q = 0; q < 4; ++q) f[q] = s[q];
    const float* fs = (const float*)f;
#pragma unroll
    for (int j = 0; j < 16; ++j) tile[(nq + j) * 72 + k] = (bf16)fs[j];
  }
  __syncthreads();
  {
    const int n = tid >> 2, kq = (tid & 3) * 16;
    bf16x8 p0 = *(const bf16x8*)(tile + n * 72 + kq);
    bf16x8 p1 = *(const bf16x8*)(tile + n * 72 + kq + 8);
    bf16* d = dst + (size_t)(nb + n) * K + kb + kq;
    *(bf16x8*)d = p0;
    *(bf16x8*)(d + 8) = p1;
  }
}

__global__ void prep_kernel(const float* __restrict__ x, bf16* __restrict__ xb,
                            const float* __restrict__ wgu, bf16* __restrict__ wguT,
                            const float* __restrict__ sgu, bf16* __restrict__ sguT,
                            const float* __restrict__ wd, bf16* __restrict__ wdT,
                            const float* __restrict__ sd, bf16* __restrict__ sdT,
                            const float* __restrict__ gw,
                            int* __restrict__ topk_e, float* __restrict__ topk_w,
                            int* __restrict__ counts, int* __restrict__ tok,
                            float* __restrict__ wt, int* __restrict__ slot) {
  __shared__ __align__(16) bf16 tile[64 * 72];
  const int b = blockIdx.x, tid = threadIdx.x;

  if (b < 4352) {            // ---- T1: [1024][1024] fp32 -> [1024][1024] bf16 T
    const int z = b >> 8, r = b & 255;
    const float* src = (z < E_NUM) ? (wgu + (size_t)z * H_DIM * 2 * I_DIM) : sgu;
    bf16*       dst  = (z < E_NUM) ? (wguT + (size_t)z * H_DIM * 2 * I_DIM) : sguT;
    transpose_tile(src, dst, H_DIM, 2 * I_DIM, (r >> 4) * 64, (r & 15) * 64, tid, tile);
  } else if (b < 6528) {     // ---- T2: [512][1024] fp32 -> [1024][512] bf16 T
    const int i = b - 4352, z = i >> 7, r = i & 127;
    const float* src = (z < E_NUM) ? (wd + (size_t)z * I_DIM * H_DIM) : sd;
    bf16*       dst  = (z < E_NUM) ? (wdT + (size_t)z * I_DIM * H_DIM) : sdT;
    transpose_tile(src, dst, I_DIM, H_DIM, (r >> 4) * 64, (r & 15) * 64, tid, tile);
  } else if (b < 7040) {     // ---- convx
    const int i = (b - 6528) * 256 + tid;
    float4 f0 = ((const float4*)x)[i * 2];
    float4 f1 = ((const float4*)x)[i * 2 + 1];
    bf16x8 p;
    p[0]=(bf16)f0.x; p[1]=(bf16)f0.y; p[2]=(bf16)f0.z; p[3]=(bf16)f0.w;
    p[4]=(bf16)f1.x; p[5]=(bf16)f1.y; p[6]=(bf16)f1.z; p[7]=(bf16)f1.w;
    ((bf16x8*)xb)[i] = p;
  } else if (b < 7296) {     // ---- router_score
    const int wave = tid >> 6, lane = tid & 63;
    const int t = (b - 7040) * 4 + wave;
    const float4* xr = (const float4*)(x + (size_t)t * H_DIM);
    float4 xv[4];
#pragma unroll
    for (int j = 0; j < 4; ++j) xv[j] = xr[lane + 64 * j];
    float p[E_NUM];
#pragma unroll
    for (int e = 0; e < E_NUM; ++e) {
      const float4* gr = (const float4*)(gw + (size_t)e * H_DIM);
      float s = 0.f;
#pragma unroll
      for (int j = 0; j < 4; ++j) {
        float4 g = gr[lane + 64 * j];
        s += xv[j].x * g.x + xv[j].y * g.y + xv[j].z * g.z + xv[j].w * g.w;
      }
      p[e] = s;
    }
#pragma unroll
    for (int off = 32; off > 0; off >>= 1) {
#pragma unroll
      for (int e = 0; e < E_NUM; ++e) p[e] += __shfl_xor(p[e], off);
    }
    float rem[E_NUM];
#pragma unroll
    for (int e = 0; e < E_NUM; ++e) rem[e] = 1.f / (1.f + __expf(-p[e]));
    float vals[TOPK]; int idx[TOPK];
#pragma unroll
    for (int k = 0; k < TOPK; ++k) {
      float m = rem[0]; int mi = 0;
#pragma unroll
      for (int e = 1; e < E_NUM; ++e) {
        if (rem[e] > m) { m = rem[e]; mi = e; }
      }
      vals[k] = m; idx[k] = mi;
#pragma unroll
      for (int e = 0; e < E_NUM; ++e) rem[e] = (e == mi) ? -1e30f : rem[e];
    }
    if (lane == 0) {
      float inv = 1.f / (vals[0] + vals[1] + vals[2] + vals[3]);
      int4 ids; ids.x = idx[0]; ids.y = idx[1]; ids.z = idx[2]; ids.w = idx[3];
      float4 w4; w4.x = vals[0]*inv; w4.y = vals[1]*inv; w4.z = vals[2]*inv; w4.w = vals[3]*inv;
      ((int4*)topk_e)[t] = ids;
      ((float4*)topk_w)[t] = w4;
    }
  } else {                   // ---- init shared-expert list
    const int i = (b - 7296) * 256 + tid;
    if (i == 0) counts[E_NUM] = T_TOK;
    tok [E_NUM * T_TOK + i] = i;
    wt  [E_NUM * T_TOK + i] = 1.0f;
    slot[E_NUM * T_TOK + i] = T_TOK * TOPK + i;
  }
}

// ---------------- router phase 2: per-expert list build via ballot prefix ----------------
__global__ void router_build_kernel(const int* __restrict__ topk_e, const float* __restrict__ topk_w,
                                    int* __restrict__ counts, int* __restrict__ tok,
                                    float* __restrict__ wt, int* __restrict__ slot) {
  const int e = blockIdx.x;  // 0..15
  const int tid = threadIdx.x, wave = tid >> 6, lane = tid & 63;
  __shared__ int wsum[4];
  int base = 0;
  for (int r = 0; r < 4; ++r) {
    int t = r * 256 + tid;
    int4 ids = ((const int4*)topk_e)[t];
    int match = -1;
    if (ids.x == e) match = 0;
    if (ids.y == e) match = 1;
    if (ids.z == e) match = 2;
    if (ids.w == e) match = 3;
    unsigned long long bm = __ballot(match >= 0);
    int prefix = __popcll(bm & ((1ull << lane) - 1ull));
    if (lane == 0) wsum[wave] = __popcll(bm);
    __syncthreads();
    int wbase = 0;
#pragma unroll
    for (int wv = 0; wv < 4; ++wv) wbase += (wv < wave) ? wsum[wv] : 0;
    int total = wsum[0] + wsum[1] + wsum[2] + wsum[3];
    if (match >= 0) {
      int pos = base + wbase + prefix;
      tok [e * T_TOK + pos] = t;
      wt  [e * T_TOK + pos] = topk_w[t * 4 + match];
      slot[e * T_TOK + pos] = t * 4 + match;
    }
    base += total;
    __syncthreads();
  }
  if (tid == 0) counts[e] = base;
}

// ---------------- GEMM1: Xb gathered @ WguT -> wt*swiglu -> h bf16 ----------------
// BM=64, BN=64(g)+64(u), BK=32, 4 waves (2x2). 3-buffer counted-vmcnt pipeline:
// stage t+2 issued BEFORE waiting vmcnt(6) -> 2 compute phases of latency cover.
__global__ __launch_bounds__(256, 4)
void gemm1_kernel(const bf16* __restrict__ xb, const bf16* __restrict__ wguT,
                  const bf16* __restrict__ sguT, const int* __restrict__ counts,
                  const int* __restrict__ tok, const float* __restrict__ wt,
                  const int* __restrict__ slot, bf16* __restrict__ hbuf) {
  const int e   = blockIdx.z;
  const int cnt = counts[e];
  const int rt  = blockIdx.y;
  if (rt * 64 >= cnt) return;
  const int nb = blockIdx.x * 64;
  const bf16* BT = (e < E_NUM) ? (wguT + (size_t)e * (2 * I_DIM) * H_DIM) : sguT;

  __shared__ __align__(16) bf16 sA[3][64 * 32];
  __shared__ __align__(16) bf16 sG[3][64 * 32];
  __shared__ __align__(16) bf16 sU[3][64 * 32];

  const int tid = threadIdx.x, wave = tid >> 6, lane = tid & 63;
  const int wr = wave >> 1, wc = wave & 1;
  const int fr = lane & 15, kg = lane >> 4;
  const int lr = lane >> 2, lk = (lane & 3) * 8;

  int ar = rt * 64 + wave * 16 + lr;
  int arc = ar < cnt ? ar : cnt - 1;
  const bf16* aS = xb + (size_t)tok[e * T_TOK + arc] * H_DIM + lk;
  const bf16* gS = BT + (size_t)(nb + wave * 16 + lr) * H_DIM + lk;
  const bf16* uS = BT + (size_t)(I_DIM + nb + wave * 16 + lr) * H_DIM + lk;
  const int ldsOff = wave * 512;

  f32x4 accg[2][2], accu[2][2];
#pragma unroll
  for (int i = 0; i < 2; ++i)
#pragma unroll
    for (int j = 0; j < 2; ++j) { accg[i][j] = f32x4{0,0,0,0}; accu[i][j] = f32x4{0,0,0,0}; }

#define STG1(t, bidx) do { int ko = (t) * 32;   \
    GLOAD16(aS + ko, sA[bidx] + ldsOff);        \
    GLOAD16(gS + ko, sG[bidx] + ldsOff);        \
    GLOAD16(uS + ko, sU[bidx] + ldsOff); } while (0)

  STG1(0, 0); STG1(1, 1);
  const int NT = H_DIM / 32;  // 32
  int bufc = 0;
  for (int t = 0; t < NT; ++t) {
    int bn = bufc + 2; bn = bn >= 3 ? bn - 3 : bn;
    if (t + 2 < NT) {
      STG1(t + 2, bn);
      asm volatile("s_waitcnt vmcnt(6)" ::: "memory");   // tile t done; t+1,t+2 in flight
    } else if (t + 1 < NT) {
      asm volatile("s_waitcnt vmcnt(3)" ::: "memory");
    } else {
      asm volatile("s_waitcnt vmcnt(0)" ::: "memory");
    }
    __builtin_amdgcn_s_barrier();
    __builtin_amdgcn_sched_barrier(0);
    const bf16* A = sA[bufc];
    const bf16* G = sG[bufc];
    const bf16* U = sU[bufc];
    bf16x8 a0 = *(const bf16x8*)(A + (wr * 32      + fr) * 32 + kg * 8);
    bf16x8 a1 = *(const bf16x8*)(A + (wr * 32 + 16 + fr) * 32 + kg * 8);
    bf16x8 g0 = *(const bf16x8*)(G + (wc * 32      + fr) * 32 + kg * 8);
    bf16x8 g1 = *(const bf16x8*)(G + (wc * 32 + 16 + fr) * 32 + kg * 8);
    bf16x8 u0 = *(const bf16x8*)(U + (wc * 32      + fr) * 32 + kg * 8);
    bf16x8 u1 = *(const bf16x8*)(U + (wc * 32 + 16 + fr) * 32 + kg * 8);
    accg[0][0] = __builtin_amdgcn_mfma_f32_16x16x32_bf16(a0, g0, accg[0][0], 0, 0, 0);
    accg[0][1] = __builtin_amdgcn_mfma_f32_16x16x32_bf16(a0, g1, accg[0][1], 0, 0, 0);
    accg[1][0] = __builtin_amdgcn_mfma_f32_16x16x32_bf16(a1, g0, accg[1][0], 0, 0, 0);
    accg[1][1] = __builtin_amdgcn_mfma_f32_16x16x32_bf16(a1, g1, accg[1][1], 0, 0, 0);
    accu[0][0] = __builtin_amdgcn_mfma_f32_16x16x32_bf16(a0, u0, accu[0][0], 0, 0, 0);
    accu[0][1] = __builtin_amdgcn_mfma_f32_16x16x32_bf16(a0, u1, accu[0][1], 0, 0, 0);
    accu[1][0] = __builtin_amdgcn_mfma_f32_16x16x32_bf16(a1, u0, accu[1][0], 0, 0, 0);
    accu[1][1] = __builtin_amdgcn_mfma_f32_16x16x32_bf16(a1, u1, accu[1][1], 0, 0, 0);
    __builtin_amdgcn_sched_barrier(0);
    __builtin_amdgcn_s_barrier();
    bufc = bufc == 2 ? 0 : bufc + 1;
  }
#undef STG1

#pragma unroll
  for (int mi = 0; mi < 2; ++mi) {
#pragma unroll
    for (int j = 0; j < 4; ++j) {
      int grow = rt * 64 + wr * 32 + mi * 16 + kg * 4 + j;
      if (grow < cnt) {
        bf16* hr = hbuf + (size_t)slot[e * T_TOK + grow] * I_DIM;
        float w = wt[e * T_TOK + grow];
#pragma unroll
        for (int ni = 0; ni < 2; ++ni) {
          float g = accg[mi][ni][j], u = accu[mi][ni][j];
          float h = w * (g / (1.f + __expf(-g))) * u;
          hr[nb + wc * 32 + ni * 16 + fr] = (bf16)h;
        }
      }
    }
  }
}

// ---------------- GEMM2: h gathered @ WdT -> plain stores into obuf[slot] ----------------
// BM=64, BN=128, BK=32, 3-buffer counted-vmcnt pipeline.
__global__ __launch_bounds__(256, 4)
void gemm2_kernel(const bf16* __restrict__ hbuf, const bf16* __restrict__ wdT,
                  const bf16* __restrict__ sdT, const int* __restrict__ counts,
                  const int* __restrict__ slot, float* __restrict__ obuf) {
  const int e   = blockIdx.z;
  const int cnt = counts[e];
  const int rt  = blockIdx.y;
  if (rt * 64 >= cnt) return;
  const int nb = blockIdx.x * 128;
  const bf16* BT = (e < E_NUM) ? (wdT + (size_t)e * H_DIM * I_DIM) : sdT;

  __shared__ __align__(16) bf16 sA[3][64 * 32];
  __shared__ __align__(16) bf16 sB[3][128 * 32];

  const int tid = threadIdx.x, wave = tid >> 6, lane = tid & 63;
  const int wr = wave >> 1, wc = wave & 1;
  const int fr = lane & 15, kg = lane >> 4;
  const int lr = lane >> 2, lk = (lane & 3) * 8;

  int ar = rt * 64 + wave * 16 + lr;
  int arc = ar < cnt ? ar : cnt - 1;
  const bf16* aS  = hbuf + (size_t)slot[e * T_TOK + arc] * I_DIM + lk;
  const bf16* bS0 = BT + (size_t)(nb + wave * 32 + lr) * I_DIM + lk;
  const bf16* bS1 = bS0 + (size_t)16 * I_DIM;
  const int aOff  = wave * 512;
  const int bOff0 = wave * 1024;
  const int bOff1 = bOff0 + 512;

  f32x4 acc[2][4];
#pragma unroll
  for (int i = 0; i < 2; ++i)
#pragma unroll
    for (int j = 0; j < 4; ++j) acc[i][j] = f32x4{0,0,0,0};

#define STG2(t, bidx) do { int ko = (t) * 32;   \
    GLOAD16(aS  + ko, sA[bidx] + aOff);         \
    GLOAD16(bS0 + ko, sB[bidx] + bOff0);        \
    GLOAD16(bS1 + ko, sB[bidx] + bOff1); } while (0)

  STG2(0, 0); STG2(1, 1);
  const int NT = I_DIM / 32;  // 16
  int bufc = 0;
  for (int t = 0; t < NT; ++t) {
    int bn = bufc + 2; bn = bn >= 3 ? bn - 3 : bn;
    if (t + 2 < NT) {
      STG2(t + 2, bn);
      asm volatile("s_waitcnt vmcnt(6)" ::: "memory");
    } else if (t + 1 < NT) {
      asm volatile("s_waitcnt vmcnt(3)" ::: "memory");
    } else {
      asm volatile("s_waitcnt vmcnt(0)" ::: "memory");
    }
    __builtin_amdgcn_s_barrier();
    __builtin_amdgcn_sched_barrier(0);
    const bf16* A = sA[bufc];
    const bf16* B = sB[bufc];
    bf16x8 a0 = *(const bf16x8*)(A + (wr * 32      + fr) * 32 + kg * 8);
    bf16x8 a1 = *(const bf16x8*)(A + (wr * 32 + 16 + fr) * 32 + kg * 8);
    bf16x8 b[4];
#pragma unroll
    for (int ni = 0; ni < 4; ++ni)
      b[ni] = *(const bf16x8*)(B + (wc * 64 + ni * 16 + fr) * 32 + kg * 8);
#pragma unroll
    for (int ni = 0; ni < 4; ++ni) {
      acc[0][ni] = __builtin_amdgcn_mfma_f32_16x16x32_bf16(a0, b[ni], acc[0][ni], 0, 0, 0);
      acc[1][ni] = __builtin_amdgcn_mfma_f32_16x16x32_bf16(a1, b[ni], acc[1][ni], 0, 0, 0);
    }
    __builtin_amdgcn_sched_barrier(0);
    __builtin_amdgcn_s_barrier();
    bufc = bufc == 2 ? 0 : bufc + 1;
  }
#undef STG2

#pragma unroll
  for (int mi = 0; mi < 2; ++mi) {
#pragma unroll
    for (int j = 0; j < 4; ++j) {
      int grow = rt * 64 + wr * 32 + mi * 16 + kg * 4 + j;
      if (grow < cnt) {
        float* orow = obuf + (size_t)slot[e * T_TOK + grow] * H_DIM + nb + wc * 64 + fr;
#pragma unroll
        for (int ni = 0; ni < 4; ++ni)
          orow[ni * 16] = acc[mi][ni][j];
      }
    }
  }
}

// ---------------- reduce: out[t] = sum_k obuf[t*4+k] + obuf[4096+t] ----------------
__global__ void reduce_kernel(const float* __restrict__ obuf, float* __restrict__ out) {
  const int t = blockIdx.x;
  const int c = threadIdx.x;
  const f32x4* o4 = (const f32x4*)obuf;
  f32x4 s = o4[(size_t)(t * 4 + 0) * 256 + c];
  s += o4[(size_t)(t * 4 + 1) * 256 + c];
  s += o4[(size_t)(t * 4 + 2) * 256 + c];
  s += o4[(size_t)(t * 4 + 3) * 256 + c];
  s += o4[(size_t)(T_TOK * TOPK + t) * 256 + c];
  ((f32x4*)out)[(size_t)t * 256 + c] = s;
}

extern "C" void kernel_launch(void* const* d_in, const int* in_sizes, int n_in,
                              void* d_out, int out_size, void* d_ws, size_t ws_size,
                              hipStream_t stream) {
  const float* x   = (const float*)d_in[0];
  const float* gw  = (const float*)d_in[1];
  const float* wgu = (const float*)d_in[2];
  const float* wd  = (const float*)d_in[3];
  const float* sgu = (const float*)d_in[4];
  const float* sd  = (const float*)d_in[5];
  float* out = (float*)d_out;

  char* ws = (char*)d_ws;
  int*   counts = (int*)  (ws);                 // 1 KB
  int*   tok    = (int*)  (ws + 1024);          // 68 KB
  float* wtA    = (float*)(ws + 70656);         // 68 KB
  int*   slotA  = (int*)  (ws + 140288);        // 68 KB
  int*   topk_e = (int*)  (ws + 209920);        // 16 KB
  float* topk_w = (float*)(ws + 226304);        // 16 KB
  bf16*  xb     = (bf16*) (ws + 245760);        // 2 MB
  bf16*  hbuf   = (bf16*) (ws + 2342912);       // 5.25 MB
  bf16*  wguT   = (bf16*) (ws + 7585792);       // 32 MB  [E][2I][H]
  bf16*  wdT    = (bf16*) (ws + 41140224);      // 16 MB  [E][H][I]
  bf16*  sguT   = (bf16*) (ws + 57917440);      // 2 MB   [2I][H]
  bf16*  sdT    = (bf16*) (ws + 60014592);      // 1 MB   [H][I]
  // obuf (20 MB fp32 [5120][1024]) aliases wguT: dead after gemm1, rewritten by
  // prep before gemm1 on every call.
  float* obuf   = (float*)(ws + 7585792);

  prep_kernel<<<7300, 256, 0, stream>>>(x, xb, wgu, wguT, sgu, sguT, wd, wdT, sd, sdT,
                                        gw, topk_e, topk_w, counts, tok, wtA, slotA);
  router_build_kernel<<<E_NUM, 256, 0, stream>>>(topk_e, topk_w, counts, tok, wtA, slotA);
  gemm1_kernel<<<dim3(8, 16, 17), 256, 0, stream>>>(xb, wguT, sguT, counts, tok, wtA, slotA, hbuf);
  gemm2_kernel<<<dim3(8, 16, 17), 256, 0, stream>>>(hbuf, wdT, sdT, counts, slotA, obuf);
  reduce_kernel<<<T_TOK, 256, 0, stream>>>(obuf, out);
}